// Round 10
// baseline (41.975 us; speedup 1.0000x reference)
//
#include <hip/hip_runtime.h>
#include <hip/hip_bf16.h>

// Problem constants
#define B_    64
#define T_    500
#define DIN   1024
#define DOUT  128
#define EPSV  1e-8f
#define BM    128          // t-rows per block
#define NKC   4            // k-chunks (exact: weighting linear in h)
#define KCL   (DIN / NKC)  // 256 k per block
#define NST   (KCL / 32)   // 8 MFMA k-steps
#define TILES 4            // ceil(500/128)
#define NGEMM (B_ * TILES * NKC)   // 1024 blocks
#define NPREP 32
#define BCOLB 528          // B LDS bytes per col: 512 + 16 pad (bank-balanced, 16B aligned)

typedef __attribute__((ext_vector_type(8))) short bf16x8;  // MFMA A/B frag
typedef __attribute__((ext_vector_type(4))) float f32x4;   // MFMA C/D frag

// Workspace layout (byte offsets)
//   wT       : bf16 [DOUT][DIN]            @ 0        (262144 B)
//   normPart : f32  [NPREP][DOUT]          @ 262144   (16384 B)
//   part     : f32  [B_][TILES][NKC][DOUT] @ 278528   (524288 B)
#define OFF_NORM  262144
#define OFF_PART  278528

__device__ inline short f2bf(float f) {
    __hip_bfloat16 h = __float2bfloat16(f);
    return __builtin_bit_cast(short, h);
}

// ---------------- prep: transpose/convert w + per-block norm partials ----------------
__global__ __launch_bounds__(512) void prep_kernel(
    const float* __restrict__ w, __hip_bfloat16* __restrict__ wT,
    float* __restrict__ normPart)
{
    const int tid = threadIdx.x;
    const int blk = blockIdx.x;
    const int t   = blk * 512 + tid;
    const int d   = t & 127;
    const int kq  = t >> 7;                 // global 8-k group, 0..127
    float v[8];
    float ss = 0.f;
#pragma unroll
    for (int m = 0; m < 8; ++m) {
        v[m] = w[(size_t)(kq * 8 + m) * DOUT + d];
        ss += v[m] * v[m];
    }
    bf16x8 o;
#pragma unroll
    for (int m = 0; m < 8; ++m) o[m] = f2bf(v[m]);
    *reinterpret_cast<bf16x8*>(wT + (size_t)d * DIN + kq * 8) = o;

    __shared__ float red[512];
    red[tid] = ss;
    __syncthreads();
    if (tid < 128)
        normPart[blk * DOUT + tid] = red[tid] + red[tid + 128] + red[tid + 256] + red[tid + 384];
}

// ---------------- main: wave-autonomous GEMM, B-in-LDS-once, no k-loop barriers ----------------
// 1024 blocks = 64 b x 4 t-tiles x 4 k-chunks; 512 threads = 8 waves.
// Stage B chunk (128 cols x 256 k bf16) into LDS ONCE -> one barrier -> each wave
// independently streams its 16 rows of x (A frags direct from global, line-optimal)
// against all 128 cols, acc[8] f32x4 in registers. Epilogue: weighted row-reduce,
// cross-wave LDS sum, one partial[128] per block.
__global__ __launch_bounds__(512, 4) void gemm_kernel(
    const float* __restrict__ x, const float* __restrict__ beta,
    const __hip_bfloat16* __restrict__ wT, float* __restrict__ partials)
{
    __shared__ __align__(16) char bsh[DOUT * BCOLB];  // 67584 B
    __shared__ float red[8][DOUT];                    // 4096 B cross-wave reduce

    const int tid  = threadIdx.x;
    const int wid  = tid >> 6;
    const int lane = tid & 63;
    const int arow = lane & 15;
    const int kblk = lane >> 4;

    const int wg   = blockIdx.x;
    const int kc   = wg & 3;
    const int tile = (wg >> 2) & 3;
    const int b    = wg >> 4;
    const int t0   = tile * BM;
    const int kbase = kc * KCL;

    // ---- stage B once: thread owns col=tid>>2, 8 chunks of 8 k-elems ----
    {
        const int col = tid >> 2;
        const int c4  = tid & 3;
        const __hip_bfloat16* src = wT + (size_t)col * DIN + kbase;
#pragma unroll
        for (int j = 0; j < 8; ++j) {
            int e = c4 * 8 + j * 32;           // element offset in [0,256)
            bf16x8 v = *reinterpret_cast<const bf16x8*>(src + e);
            *reinterpret_cast<bf16x8*>(bsh + col * BCOLB + e * 2) = v;
        }
    }
    __syncthreads();   // the ONLY pre-epilogue barrier

    // ---- per-wave autonomous k-loop ----
    const int trow_raw = t0 + wid * 16 + arow;
    const int trow = trow_raw < T_ ? trow_raw : T_ - 1;   // clamp; weight=0 kills it
    const float* ax = x + ((size_t)b * T_ + trow) * DIN + kbase + kblk * 8;

    // B fragment base offsets per 16-col group (k advances as +s*64 immediate)
    int bro[8];
#pragma unroll
    for (int fn = 0; fn < 8; ++fn)
        bro[fn] = (fn * 16 + arow) * BCOLB + kblk * 16;

    f32x4 acc[8] = {};

    float4 a0 = *reinterpret_cast<const float4*>(ax);
    float4 a1 = *reinterpret_cast<const float4*>(ax + 4);
#pragma unroll
    for (int s = 0; s < NST; ++s) {
        float4 n0, n1;
        if (s + 1 < NST) {                       // prefetch next step's A early
            n0 = *reinterpret_cast<const float4*>(ax + (s + 1) * 32);
            n1 = *reinterpret_cast<const float4*>(ax + (s + 1) * 32 + 4);
        }
        bf16x8 af;
        af[0] = f2bf(a0.x); af[1] = f2bf(a0.y); af[2] = f2bf(a0.z); af[3] = f2bf(a0.w);
        af[4] = f2bf(a1.x); af[5] = f2bf(a1.y); af[6] = f2bf(a1.z); af[7] = f2bf(a1.w);
#pragma unroll
        for (int fn = 0; fn < 8; ++fn) {
            bf16x8 bf = *reinterpret_cast<const bf16x8*>(bsh + bro[fn] + s * 64);
            acc[fn] = __builtin_amdgcn_mfma_f32_16x16x32_bf16(af, bf, acc[fn], 0, 0, 0);
        }
        if (s + 1 < NST) { a0 = n0; a1 = n1; }
    }

    // ---- epilogue: weighted row-reduction (weights 1-beta^(T-t) on the fly) ----
    // C frag: col = lane&15 (within 16-col group), row = kblk*4 + r  [verified]
#pragma unroll
    for (int fn = 0; fn < 8; ++fn) {
        const int col = fn * 16 + arow;
        const float lb = log2f(beta[col]);   // beta in [0,1): log2(0) = -inf -> weight 1
        float s = 0.f;
#pragma unroll
        for (int r = 0; r < 4; ++r) {
            int t = t0 + wid * 16 + kblk * 4 + r;
            if (t < T_)
                s += (1.f - exp2f((float)(T_ - t) * lb)) * acc[fn][r];
        }
        s += __shfl_xor(s, 16);
        s += __shfl_xor(s, 32);
        if (kblk == 0) red[wid][col] = s;
    }
    __syncthreads();

    if (tid < DOUT) {
        float v = 0.f;
#pragma unroll
        for (int ww = 0; ww < 8; ++ww) v += red[ww][tid];
        partials[(((size_t)b * TILES + tile) * NKC + kc) * DOUT + tid] = v;
    }
}

// ---------------- finalize: norm from partials, sum, scale, bias ----------------
__global__ __launch_bounds__(256) void finalize_kernel(
    const float* __restrict__ partials, const float* __restrict__ normPart,
    const float* __restrict__ bias, float* __restrict__ out)
{
    int i = blockIdx.x * 256 + threadIdx.x;  // 8192 = B_*DOUT
    int b = i >> 7, d = i & 127;
    float nrm = 0.f;
#pragma unroll
    for (int g = 0; g < NPREP; ++g)
        nrm += normPart[g * DOUT + d];
    float scale = 1.f / ((nrm + EPSV) * (float)T_);
    float s = 0.f;
#pragma unroll
    for (int p = 0; p < TILES * NKC; ++p)
        s += partials[((size_t)b * TILES * NKC + p) * DOUT + d];
    out[i] = s * scale - bias[d];
}

extern "C" void kernel_launch(void* const* d_in, const int* in_sizes, int n_in,
                              void* d_out, int out_size, void* d_ws, size_t ws_size,
                              hipStream_t stream) {
    const float* x    = (const float*)d_in[0];  // [64][500][1024]
    const float* w    = (const float*)d_in[1];  // [1024][128]
    const float* beta = (const float*)d_in[2];  // [128]
    const float* bias = (const float*)d_in[3];  // [128]
    float* out = (float*)d_out;                 // [64][128] fp32

    char* ws = (char*)d_ws;
    __hip_bfloat16* wT = (__hip_bfloat16*)(ws);
    float* normPart = (float*)(ws + OFF_NORM);
    float* partials = (float*)(ws + OFF_PART);

    prep_kernel<<<NPREP, 512, 0, stream>>>(w, wT, normPart);
    gemm_kernel<<<NGEMM, 512, 0, stream>>>(x, beta, wT, partials);
    finalize_kernel<<<(B_ * DOUT) / 256, 256, 0, stream>>>(partials, normPart, bias, out);
}

// Round 11
// 40.830 us; speedup vs baseline: 1.0280x; 1.0280x over previous
//
#include <hip/hip_runtime.h>
#include <hip/hip_bf16.h>

// Problem constants
#define B_    64
#define T_    500
#define DIN   1024
#define DOUT  128
#define EPSV  1e-8f
#define BM    128          // t-rows per block
#define NKC   4            // k-chunks (exact: weighting linear in h)
#define KCL   (DIN / NKC)  // 256 k per block
#define NST   (KCL / 32)   // 8 MFMA k-steps
#define TILES 4            // ceil(500/128)
#define NGEMM (B_ * TILES * NKC)   // 1024 blocks
#define NPREP 32
#define BCOLB 528          // B LDS bytes per col: 512 + 16 pad (bank-balanced, 16B aligned)

typedef __attribute__((ext_vector_type(8))) short bf16x8;  // MFMA A/B frag
typedef __attribute__((ext_vector_type(4))) float f32x4;   // MFMA C/D frag

// Workspace layout (byte offsets)
//   wT       : bf16 [DOUT][DIN]            @ 0        (262144 B)
//   normPart : f32  [NPREP][DOUT]          @ 262144   (16384 B)
//   part     : f32  [B_][TILES][NKC][DOUT] @ 278528   (524288 B)
#define OFF_NORM  262144
#define OFF_PART  278528

__device__ inline short f2bf(float f) {
    __hip_bfloat16 h = __float2bfloat16(f);
    return __builtin_bit_cast(short, h);
}

// ---------------- prep: transpose/convert w + per-block norm partials ----------------
__global__ __launch_bounds__(512) void prep_kernel(
    const float* __restrict__ w, __hip_bfloat16* __restrict__ wT,
    float* __restrict__ normPart)
{
    const int tid = threadIdx.x;
    const int blk = blockIdx.x;
    const int t   = blk * 512 + tid;
    const int d   = t & 127;
    const int kq  = t >> 7;                 // global 8-k group, 0..127
    float v[8];
    float ss = 0.f;
#pragma unroll
    for (int m = 0; m < 8; ++m) {
        v[m] = w[(size_t)(kq * 8 + m) * DOUT + d];
        ss += v[m] * v[m];
    }
    bf16x8 o;
#pragma unroll
    for (int m = 0; m < 8; ++m) o[m] = f2bf(v[m]);
    *reinterpret_cast<bf16x8*>(wT + (size_t)d * DIN + kq * 8) = o;

    __shared__ float red[512];
    red[tid] = ss;
    __syncthreads();
    if (tid < 128)
        normPart[blk * DOUT + tid] = red[tid] + red[tid + 128] + red[tid + 256] + red[tid + 384];
}

// ---------------- main: wave-autonomous GEMM, B-in-LDS-once, 4-deep A prefetch ----------------
// 1024 blocks = 64 b x 4 t-tiles x 4 k-chunks; 512 threads = 8 waves.
// Stage B chunk (128 cols x 256 k bf16) into LDS ONCE -> one barrier -> each wave
// independently streams its 16 rows of x with a 4-slot register prefetch queue
// (8 16B-loads in flight per wave), acc[8] f32x4 in registers.
__global__ __launch_bounds__(512, 4) void gemm_kernel(
    const float* __restrict__ x, const float* __restrict__ beta,
    const __hip_bfloat16* __restrict__ wT, float* __restrict__ partials)
{
    __shared__ __align__(16) char bsh[DOUT * BCOLB];  // 67584 B
    __shared__ float red[8][DOUT];                    // 4096 B cross-wave reduce

    const int tid  = threadIdx.x;
    const int wid  = tid >> 6;
    const int lane = tid & 63;
    const int arow = lane & 15;
    const int kblk = lane >> 4;

    const int wg   = blockIdx.x;
    const int kc   = wg & 3;
    const int tile = (wg >> 2) & 3;
    const int b    = wg >> 4;
    const int t0   = tile * BM;
    const int kbase = kc * KCL;

    // ---- stage B once: thread owns col=tid>>2, 8 chunks of 8 k-elems ----
    {
        const int col = tid >> 2;
        const int c4  = tid & 3;
        const __hip_bfloat16* src = wT + (size_t)col * DIN + kbase;
#pragma unroll
        for (int j = 0; j < 8; ++j) {
            int e = c4 * 8 + j * 32;           // element offset in [0,256)
            bf16x8 v = *reinterpret_cast<const bf16x8*>(src + e);
            *reinterpret_cast<bf16x8*>(bsh + col * BCOLB + e * 2) = v;
        }
    }
    __syncthreads();   // the ONLY pre-epilogue barrier

    // ---- per-wave autonomous k-loop, 4-deep static prefetch queue ----
    const int trow_raw = t0 + wid * 16 + arow;
    const int trow = trow_raw < T_ ? trow_raw : T_ - 1;   // clamp; weight=0 kills it
    const float* ax = x + ((size_t)b * T_ + trow) * DIN + kbase + kblk * 8;

    // B fragment base offsets per 16-col group (k advances as +s*64 immediate)
    int bro[8];
#pragma unroll
    for (int fn = 0; fn < 8; ++fn)
        bro[fn] = (fn * 16 + arow) * BCOLB + kblk * 16;

    f32x4 acc[8] = {};

    // 4 static queue slots (rule #20: every access compile-time named)
    float4 q0_0, q0_1, q1_0, q1_1, q2_0, q2_1, q3_0, q3_1;
    q0_0 = *reinterpret_cast<const float4*>(ax);
    q0_1 = *reinterpret_cast<const float4*>(ax + 4);
    q1_0 = *reinterpret_cast<const float4*>(ax + 32);
    q1_1 = *reinterpret_cast<const float4*>(ax + 36);
    q2_0 = *reinterpret_cast<const float4*>(ax + 64);
    q2_1 = *reinterpret_cast<const float4*>(ax + 68);
    q3_0 = *reinterpret_cast<const float4*>(ax + 96);
    q3_1 = *reinterpret_cast<const float4*>(ax + 100);

#define STEP(S, SL) { \
    bf16x8 af; \
    af[0]=f2bf(q##SL##_0.x); af[1]=f2bf(q##SL##_0.y); af[2]=f2bf(q##SL##_0.z); af[3]=f2bf(q##SL##_0.w); \
    af[4]=f2bf(q##SL##_1.x); af[5]=f2bf(q##SL##_1.y); af[6]=f2bf(q##SL##_1.z); af[7]=f2bf(q##SL##_1.w); \
    if ((S) + 4 < NST) { \
        q##SL##_0 = *reinterpret_cast<const float4*>(ax + ((S) + 4) * 32); \
        q##SL##_1 = *reinterpret_cast<const float4*>(ax + ((S) + 4) * 32 + 4); \
    } \
    _Pragma("unroll") \
    for (int fn = 0; fn < 8; ++fn) { \
        bf16x8 bf = *reinterpret_cast<const bf16x8*>(bsh + bro[fn] + (S) * 64); \
        acc[fn] = __builtin_amdgcn_mfma_f32_16x16x32_bf16(af, bf, acc[fn], 0, 0, 0); \
    } }

    STEP(0, 0) STEP(1, 1) STEP(2, 2) STEP(3, 3)
    STEP(4, 0) STEP(5, 1) STEP(6, 2) STEP(7, 3)
#undef STEP

    // ---- epilogue: weighted row-reduction (weights 1-beta^(T-t) on the fly) ----
    // C frag: col = lane&15 (within 16-col group), row = kblk*4 + r  [verified]
#pragma unroll
    for (int fn = 0; fn < 8; ++fn) {
        const int col = fn * 16 + arow;
        const float lb = log2f(beta[col]);   // beta in [0,1): log2(0) = -inf -> weight 1
        float s = 0.f;
#pragma unroll
        for (int r = 0; r < 4; ++r) {
            int t = t0 + wid * 16 + kblk * 4 + r;
            if (t < T_)
                s += (1.f - exp2f((float)(T_ - t) * lb)) * acc[fn][r];
        }
        s += __shfl_xor(s, 16);
        s += __shfl_xor(s, 32);
        if (kblk == 0) red[wid][col] = s;
    }
    __syncthreads();

    if (tid < DOUT) {
        float v = 0.f;
#pragma unroll
        for (int ww = 0; ww < 8; ++ww) v += red[ww][tid];
        partials[(((size_t)b * TILES + tile) * NKC + kc) * DOUT + tid] = v;
    }
}

// ---------------- finalize: norm from partials, sum, scale, bias ----------------
__global__ __launch_bounds__(256) void finalize_kernel(
    const float* __restrict__ partials, const float* __restrict__ normPart,
    const float* __restrict__ bias, float* __restrict__ out)
{
    int i = blockIdx.x * 256 + threadIdx.x;  // 8192 = B_*DOUT
    int b = i >> 7, d = i & 127;
    float nrm = 0.f;
#pragma unroll
    for (int g = 0; g < NPREP; ++g)
        nrm += normPart[g * DOUT + d];
    float scale = 1.f / ((nrm + EPSV) * (float)T_);
    float s = 0.f;
#pragma unroll
    for (int p = 0; p < TILES * NKC; ++p)
        s += partials[((size_t)b * TILES * NKC + p) * DOUT + d];
    out[i] = s * scale - bias[d];
}

extern "C" void kernel_launch(void* const* d_in, const int* in_sizes, int n_in,
                              void* d_out, int out_size, void* d_ws, size_t ws_size,
                              hipStream_t stream) {
    const float* x    = (const float*)d_in[0];  // [64][500][1024]
    const float* w    = (const float*)d_in[1];  // [1024][128]
    const float* beta = (const float*)d_in[2];  // [128]
    const float* bias = (const float*)d_in[3];  // [128]
    float* out = (float*)d_out;                 // [64][128] fp32

    char* ws = (char*)d_ws;
    __hip_bfloat16* wT = (__hip_bfloat16*)(ws);
    float* normPart = (float*)(ws + OFF_NORM);
    float* partials = (float*)(ws + OFF_PART);

    prep_kernel<<<NPREP, 512, 0, stream>>>(w, wT, normPart);
    gemm_kernel<<<NGEMM, 512, 0, stream>>>(x, beta, wT, partials);
    finalize_kernel<<<(B_ * DOUT) / 256, 256, 0, stream>>>(partials, normPart, bias, out);
}